// Round 13
// baseline (309.522 us; speedup 1.0000x reference)
//
#include <hip/hip_runtime.h>
#include <hip/hip_bf16.h>
#include <stdint.h>

#define CHUNKC 32
#define PRIORC 64
#define POSEC 512
#define PREDC 128
#define NB 2048
#define K1 (CHUNKC*POSEC)   // 16384
#define KS 8                // split-K factor (bf16 partials)
#define KCH (K1/KS)         // 2048

typedef __attribute__((ext_vector_type(8))) short bf16x8;
typedef __attribute__((ext_vector_type(8))) unsigned short u16x8;
typedef __attribute__((ext_vector_type(4))) float f32x4;
typedef __attribute__((ext_vector_type(4))) float f4v;

__device__ __forceinline__ unsigned short f2b(float f) {
    union { float f; unsigned int u; } x; x.f = f;
    unsigned int r = x.u + 0x7fffu + ((x.u >> 16) & 1u);
    return (unsigned short)(r >> 16);
}
__device__ __forceinline__ float b2f(unsigned short u) {
    union { unsigned int i; float f; } x; x.i = ((unsigned int)u) << 16; return x.f;
}
__device__ __forceinline__ unsigned short cf(float f) {
    __hip_bfloat16 h = __float2bfloat16(f);
    union { __hip_bfloat16 h; unsigned short u; } x; x.h = h; return x.u;
}

__device__ __forceinline__ void gload_lds16(const void* g, void* l) {
    __builtin_amdgcn_global_load_lds(
        (const __attribute__((address_space(1))) unsigned int*)g,
        (__attribute__((address_space(3))) unsigned int*)l, 16, 0, 0);
}

// ---------------- cvt_w: W1, W2 -> bf16 ----------------
#define W1N4  2097152   // 512*16384/4
#define W2N4  65536     // 512*512/4
__global__ __launch_bounds__(256) void cvt_w_kernel(const float4* __restrict__ W1,
                                                    const float4* __restrict__ W2,
                                                    ushort4* __restrict__ w1b,
                                                    ushort4* __restrict__ w2b) {
    const int64_t n = W1N4 + W2N4;
    const int64_t stride = (int64_t)gridDim.x * blockDim.x;
    for (int64_t i = (int64_t)blockIdx.x * blockDim.x + threadIdx.x; i < n; i += stride) {
        float4 v; ushort4* dst;
        if (i < W1N4) { v = W1[i]; dst = w1b + i; }
        else          { v = W2[i - W1N4]; dst = w2b + (i - W1N4); }
        *dst = make_ushort4(f2b(v.x), f2b(v.y), f2b(v.z), f2b(v.w));
    }
}

// ---------------- GEMM1: bf16 partials of x @ W1^T (R12-proven) ----------------
// BM=128, BN=256, BK=64, 8 waves. A staged f32 via gload_lds (A issues FIRST:
// HBM-latency loads get head start; B is L2-hot), cvt on LDS->reg read. 2-phase
// dbuf + T2 swizzle. grid = 16mt*2nt*8ks = 256; XCD swizzle: one ks layer/XCD.
__global__ __launch_bounds__(512) void gemm1_kernel(const float* __restrict__ init,
                                                    const ushort* __restrict__ w1b,
                                                    ushort* __restrict__ part) {
    __shared__ float  As[2][128][64];   // 2 x 32 KB f32
    __shared__ ushort Bs[2][256][64];   // 2 x 32 KB bf16
    const int t = threadIdx.x;
    const int l = t & 63, wid = t >> 6;
    const int wr = wid >> 2, wc = wid & 3;
    const int orig = (blockIdx.x & 7) * 32 + (blockIdx.x >> 3);
    const int mt = orig & 15, nt = (orig >> 4) & 1, ks = orig >> 5;
    const int NIT = KCH / 64;                       // 32

    f32x4 acc[4][4] = {};

    const float*  aG = init + (int64_t)(mt * 128) * 32768 + 16384 + ks * KCH;
    const ushort* bG = w1b + (int64_t)(nt * 256) * K1 + ks * KCH;

    const int arow  = t >> 4;
    const int aslot = (t & 15) ^ ((t >> 4) & 15);   // pre-swizzled source slot
    const int brow = t >> 3;
    const int bcol = ((t & 7) ^ ((t >> 3) & 7)) * 8;

    const int fr = l & 15, fq = l >> 4;
    const int cxB = fr & 7;

    // prologue: stage tile 0 (A first: long-latency HBM loads)
#pragma unroll
    for (int i = 0; i < 4; ++i)
        gload_lds16(aG + (int64_t)(i * 32 + arow) * 32768 + aslot * 4,
                    (char*)&As[0][0][0] + i * 8192 + wid * 1024);
#pragma unroll
    for (int i = 0; i < 4; ++i)
        gload_lds16(bG + (int64_t)(i * 64 + brow) * K1 + bcol,
                    (char*)&Bs[0][0][0] + i * 8192 + wid * 1024);

    for (int it = 0; it < NIT; ++it) {
        const int cur = it & 1;
        __syncthreads();    // drains buf[cur]'s loads (one iteration of cover)
        if (it + 1 < NIT) {
            const int nxt = cur ^ 1;
            const int k0 = (it + 1) * 64;
#pragma unroll
            for (int i = 0; i < 4; ++i)
                gload_lds16(aG + (int64_t)(i * 32 + arow) * 32768 + k0 + aslot * 4,
                            (char*)&As[nxt][0][0] + i * 8192 + wid * 1024);
#pragma unroll
            for (int i = 0; i < 4; ++i)
                gload_lds16(bG + (int64_t)(i * 64 + brow) * K1 + k0 + bcol,
                            (char*)&Bs[nxt][0][0] + i * 8192 + wid * 1024);
        }
#pragma unroll
        for (int k2 = 0; k2 < 2; ++k2) {
            bf16x8 a[4], b[4];
            const int s0 = k2 * 8 + fq * 2;
#pragma unroll
            for (int m = 0; m < 4; ++m) {
                const int r = wr * 64 + m * 16 + fr;        // r&15 == fr
                f32x4 va = *(const f32x4*)&As[cur][r][((s0    ) ^ fr) * 4];
                f32x4 vb = *(const f32x4*)&As[cur][r][((s0 + 1) ^ fr) * 4];
                u16x8 w;
                w[0] = cf(va[0]); w[1] = cf(va[1]); w[2] = cf(va[2]); w[3] = cf(va[3]);
                w[4] = cf(vb[0]); w[5] = cf(vb[1]); w[6] = cf(vb[2]); w[7] = cf(vb[3]);
                union { u16x8 u; bf16x8 b; } cvtu; cvtu.u = w;
                a[m] = cvtu.b;
            }
            const int cs = ((k2 * 4 + fq) ^ cxB) * 8;
#pragma unroll
            for (int n = 0; n < 4; ++n)
                b[n] = *(const bf16x8*)&Bs[cur][wc * 64 + n * 16 + fr][cs];
#pragma unroll
            for (int m = 0; m < 4; ++m)
#pragma unroll
                for (int n = 0; n < 4; ++n)
                    acc[m][n] = __builtin_amdgcn_mfma_f32_16x16x32_bf16(a[m], b[n], acc[m][n], 0, 0, 0);
        }
    }

    ushort* P = part + (int64_t)ks * NB * POSEC;
    const int mbase = mt * 128 + wr * 64, nbase = nt * 256 + wc * 64;
#pragma unroll
    for (int m = 0; m < 4; ++m)
#pragma unroll
        for (int n = 0; n < 4; ++n) {
            int row0 = mbase + m * 16 + fq * 4;
            int col  = nbase + n * 16 + fr;
#pragma unroll
            for (int r = 0; r < 4; ++r)
                P[(int64_t)(row0 + r) * POSEC + col] = f2b(acc[m][n][r]);
        }
}

// ---------------- GEMM2 (fused reduce): mem = (sum_ks part + b1) @ W2b^T + b2 ----------------
// A-tile staged by reg-fused reduction: read 8 bf16 partials, f32-sum, +b1, cvt,
// swizzled ds_write_b128 (phys slot = logical ^ (row&7), same involution as read).
// B via gload_lds with pre-swizzled source (R9-proven). 64x64 tiles, grid 256.
__global__ __launch_bounds__(256) void gemm2_kernel(const ushort* __restrict__ part,
                                                    const float* __restrict__ b1,
                                                    const ushort* __restrict__ w2b,
                                                    const float* __restrict__ b2,
                                                    float* __restrict__ mem) {
    __shared__ ushort As[64][64];
    __shared__ ushort Bs[64][64];
    const int t = threadIdx.x;
    const int l = t & 63, wid = t >> 6;
    const int wr = wid >> 1, wc = wid & 1;
    const int mt = blockIdx.x >> 3, nt = blockIdx.x & 7;

    f32x4 acc[2][2] = {};
    const ushort* bG = w2b + (int64_t)(nt * 64) * POSEC;
    const int srow = t >> 3;                       // 0..31
    const int sl   = t & 7;                        // logical 16B slot (8 bf16)
    const int scolB = (sl ^ (srow & 7)) * 8;       // B source pre-swizzle
    const int fr = l & 15, fq = l >> 4;
    const int cx = fr & 7;

    for (int k0 = 0; k0 < POSEC; k0 += 64) {
        // B: gload_lds, 2 chunks of 32 rows
#pragma unroll
        for (int i = 0; i < 2; ++i)
            gload_lds16(bG + (int64_t)(i * 32 + srow) * POSEC + k0 + scolB,
                        (char*)&Bs[0][0] + i * 4096 + wid * 1024);
        // A: fused reduce. gk = k-columns this thread covers (same for both i).
        const int gk = k0 + sl * 8;
        f4v bv0 = *(const f4v*)&b1[gk];
        f4v bv4 = *(const f4v*)&b1[gk + 4];
#pragma unroll
        for (int i = 0; i < 2; ++i) {
            const int r = i * 32 + srow;
            const int64_t base = (int64_t)(mt * 64 + r) * POSEC + gk;
            float s[8] = {};
#pragma unroll
            for (int p = 0; p < KS; ++p) {
                u16x8 v = *(const u16x8*)(part + (int64_t)p * (NB * POSEC) + base);
#pragma unroll
                for (int j = 0; j < 8; ++j) s[j] += b2f(v[j]);
            }
            u16x8 w;
#pragma unroll
            for (int j = 0; j < 4; ++j) { w[j] = f2b(s[j] + bv0[j]); w[j+4] = f2b(s[j+4] + bv4[j]); }
            *(u16x8*)&As[r][(sl ^ (r & 7)) * 8] = w;
        }
        __syncthreads();
#pragma unroll
        for (int k2 = 0; k2 < 2; ++k2) {
            const int cs = ((k2 * 4 + fq) ^ cx) * 8;
            bf16x8 a[2], b[2];
#pragma unroll
            for (int m = 0; m < 2; ++m)
                a[m] = *(const bf16x8*)&As[wr * 32 + m * 16 + fr][cs];
#pragma unroll
            for (int n = 0; n < 2; ++n)
                b[n] = *(const bf16x8*)&Bs[wc * 32 + n * 16 + fr][cs];
#pragma unroll
            for (int m = 0; m < 2; ++m)
#pragma unroll
                for (int n = 0; n < 2; ++n)
                    acc[m][n] = __builtin_amdgcn_mfma_f32_16x16x32_bf16(a[m], b[n], acc[m][n], 0, 0, 0);
        }
        __syncthreads();
    }

    const int mbase = mt * 64 + wr * 32, nbase = nt * 64 + wc * 32;
#pragma unroll
    for (int m = 0; m < 2; ++m)
#pragma unroll
        for (int n = 0; n < 2; ++n) {
            int row0 = mbase + m * 16 + fq * 4;
            int col  = nbase + n * 16 + fr;
            float bias = b2[col];
#pragma unroll
            for (int r = 0; r < 4; ++r)
                mem[(int64_t)(row0 + r) * POSEC + col] = acc[m][n][r] + bias;
        }
}

// ---------------- score + sigmoid + blend + copy ----------------
__global__ __launch_bounds__(256) void blend_kernel(const float* __restrict__ pred,
                                                    const float* __restrict__ mem,
                                                    float* __restrict__ out) {
    const int b = blockIdx.x;
    const int t = threadIdx.x;
    __shared__ float sm[POSEC];
    __shared__ float sg[CHUNKC];

    sm[t]       = mem[(int64_t)b * POSEC + t];
    sm[t + 256] = mem[(int64_t)b * POSEC + 256 + t];
    __syncthreads();

    const int l = t & 63, wid = t >> 6;
    const float4* sm4 = (const float4*)sm;
    const float4* p4 = (const float4*)pred + (int64_t)b * 16384;
    float4* o4 = (float4*)out + (int64_t)b * 16384;

#pragma unroll
    for (int ci = 0; ci < 8; ++ci) {
        int c = wid * 8 + ci;
        float4 h0 = p4[c * 128 + l * 2];
        float4 h1 = p4[c * 128 + l * 2 + 1];
        float4 m0 = sm4[l * 2];
        float4 m1 = sm4[l * 2 + 1];
        float s = h0.x * m0.x + h0.y * m0.y + h0.z * m0.z + h0.w * m0.w
                + h1.x * m1.x + h1.y * m1.y + h1.z * m1.z + h1.w * m1.w;
#pragma unroll
        for (int o = 32; o; o >>= 1) s += __shfl_xor(s, o);
        if (l == 0) sg[c] = 1.0f / (1.0f + expf(-s));
    }
    __syncthreads();

#pragma unroll
    for (int i = 0; i < 16; ++i) {
        int idx = i * 256 + t;
        int row = idx >> 7, c4 = idx & 127;
        float g = sg[row];
        float4 h = p4[idx];
        float4 m = sm4[c4];
        float4 r;
        r.x = g * h.x + (1.0f - g) * m.x;
        r.y = g * h.y + (1.0f - g) * m.y;
        r.z = g * h.z + (1.0f - g) * m.z;
        r.w = g * h.w + (1.0f - g) * m.w;
        o4[idx] = r;
    }
#pragma unroll
    for (int i = 0; i < 48; ++i) {
        int idx = 4096 + i * 256 + t;
        f4v h = __builtin_nontemporal_load((const f4v*)p4 + idx);
        __builtin_nontemporal_store(h, (f4v*)o4 + idx);
    }
}

// ---------------- launch ----------------

extern "C" void kernel_launch(void* const* d_in, const int* in_sizes, int n_in,
                              void* d_out, int out_size, void* d_ws, size_t ws_size,
                              hipStream_t stream) {
    const float* init = (const float*)d_in[0];
    const float* pred = (const float*)d_in[1];
    const float* W1   = (const float*)d_in[2];
    const float* b1   = (const float*)d_in[3];
    const float* W2   = (const float*)d_in[4];
    const float* b2   = (const float*)d_in[5];
    float* out = (float*)d_out;

    char* ws = (char*)d_ws;
    ushort* w1b  = (ushort*)(ws);                       // 16777216 B
    ushort* w2b  = (ushort*)(ws + 16777216);            //   524288 B
    ushort* part = (ushort*)(ws + 17301504);            // 16777216 B (8 x 2048x512 bf16)
    float*  mem  = (float*) (ws + 34078720);            //  4194304 B
    // total 38,273,024 B

    cvt_w_kernel<<<1024, 256, 0, stream>>>((const float4*)W1, (const float4*)W2,
                                           (ushort4*)w1b, (ushort4*)w2b);
    gemm1_kernel<<<256, 512, 0, stream>>>(init, w1b, part);
    gemm2_kernel<<<256, 256, 0, stream>>>(part, b1, w2b, b2, mem);
    blend_kernel<<<NB, 256, 0, stream>>>(pred, mem, out);
}

// Round 14
// 288.481 us; speedup vs baseline: 1.0729x; 1.0729x over previous
//
#include <hip/hip_runtime.h>
#include <hip/hip_bf16.h>
#include <stdint.h>

#define CHUNKC 32
#define PRIORC 64
#define POSEC 512
#define PREDC 128
#define NB 2048
#define K1 (CHUNKC*POSEC)   // 16384
#define KS 8                // split-K factor (bf16 partials)
#define KCH (K1/KS)         // 2048

typedef __attribute__((ext_vector_type(8))) short bf16x8;
typedef __attribute__((ext_vector_type(8))) unsigned short u16x8;
typedef __attribute__((ext_vector_type(4))) float f32x4;
typedef __attribute__((ext_vector_type(4))) float f4v;

__device__ __forceinline__ unsigned short f2b(float f) {
    union { float f; unsigned int u; } x; x.f = f;
    unsigned int r = x.u + 0x7fffu + ((x.u >> 16) & 1u);
    return (unsigned short)(r >> 16);
}
__device__ __forceinline__ float b2f(unsigned short u) {
    union { unsigned int i; float f; } x; x.i = ((unsigned int)u) << 16; return x.f;
}
__device__ __forceinline__ unsigned short cf(float f) {
    __hip_bfloat16 h = __float2bfloat16(f);
    union { __hip_bfloat16 h; unsigned short u; } x; x.h = h; return x.u;
}

__device__ __forceinline__ void gload_lds16(const void* g, void* l) {
    __builtin_amdgcn_global_load_lds(
        (const __attribute__((address_space(1))) unsigned int*)g,
        (__attribute__((address_space(3))) unsigned int*)l, 16, 0, 0);
}

// ---------------- cvt_w: W1, W2 -> bf16 ----------------
#define W1N4  2097152   // 512*16384/4
#define W2N4  65536     // 512*512/4
__global__ __launch_bounds__(256) void cvt_w_kernel(const float4* __restrict__ W1,
                                                    const float4* __restrict__ W2,
                                                    ushort4* __restrict__ w1b,
                                                    ushort4* __restrict__ w2b) {
    const int64_t n = W1N4 + W2N4;
    const int64_t stride = (int64_t)gridDim.x * blockDim.x;
    for (int64_t i = (int64_t)blockIdx.x * blockDim.x + threadIdx.x; i < n; i += stride) {
        float4 v; ushort4* dst;
        if (i < W1N4) { v = W1[i]; dst = w1b + i; }
        else          { v = W2[i - W1N4]; dst = w2b + (i - W1N4); }
        *dst = make_ushort4(f2b(v.x), f2b(v.y), f2b(v.z), f2b(v.w));
    }
}

// ---------------- GEMM1: bf16 partials of x @ W1^T ----------------
// R12 structure (BM=128, BN=256, BK=64, 8 waves, A f32-direct, T2 swizzle) with
// T4 counted-vmcnt schedule: STAGE(nxt) -> vmcnt(8) [my cur loads done] ->
// s_barrier B1 [ALL cur loads done] -> MFMA(cur) -> s_barrier B2 [readers done,
// buffer reusable]. Raw s_barrier does NOT drain vmcnt -> the 8 next-tile loads
// stay in flight across the MFMA phase (removes the __syncthreads vmcnt(0) stall).
__global__ __launch_bounds__(512) void gemm1_kernel(const float* __restrict__ init,
                                                    const ushort* __restrict__ w1b,
                                                    ushort* __restrict__ part) {
    __shared__ float  As[2][128][64];   // 2 x 32 KB f32
    __shared__ ushort Bs[2][256][64];   // 2 x 32 KB bf16
    const int t = threadIdx.x;
    const int l = t & 63, wid = t >> 6;
    const int wr = wid >> 2, wc = wid & 3;
    const int orig = (blockIdx.x & 7) * 32 + (blockIdx.x >> 3);
    const int mt = orig & 15, nt = (orig >> 4) & 1, ks = orig >> 5;
    const int NIT = KCH / 64;                       // 32

    f32x4 acc[4][4] = {};

    const float*  aG = init + (int64_t)(mt * 128) * 32768 + 16384 + ks * KCH;
    const ushort* bG = w1b + (int64_t)(nt * 256) * K1 + ks * KCH;

    const int arow  = t >> 4;
    const int aslot = (t & 15) ^ ((t >> 4) & 15);   // pre-swizzled source slot
    const int brow = t >> 3;
    const int bcol = ((t & 7) ^ ((t >> 3) & 7)) * 8;

    const int fr = l & 15, fq = l >> 4;
    const int cxB = fr & 7;

    // 8 gload_lds per thread per tile (4 A + 4 B); A first (HBM-latency head start)
    auto STAGE = [&](int buf, int k0) {
#pragma unroll
        for (int i = 0; i < 4; ++i)
            gload_lds16(aG + (int64_t)(i * 32 + arow) * 32768 + k0 + aslot * 4,
                        (char*)&As[buf][0][0] + i * 8192 + wid * 1024);
#pragma unroll
        for (int i = 0; i < 4; ++i)
            gload_lds16(bG + (int64_t)(i * 64 + brow) * K1 + k0 + bcol,
                        (char*)&Bs[buf][0][0] + i * 8192 + wid * 1024);
    };

    STAGE(0, 0);    // prologue: tile 0 -> buffer 0 (8 loads outstanding)

    for (int it = 0; it < NIT; ++it) {
        const int cur = it & 1;
        if (it + 1 < NIT) {
            STAGE(cur ^ 1, (it + 1) * 64);          // +8 loads (buf nxt) in flight
            asm volatile("s_waitcnt vmcnt(8)" ::: "memory");   // my buf[cur] done
        } else {
            asm volatile("s_waitcnt vmcnt(0)" ::: "memory");
        }
        __builtin_amdgcn_s_barrier();               // B1: ALL buf[cur] loads done
        asm volatile("" ::: "memory");
        __builtin_amdgcn_sched_barrier(0);
#pragma unroll
        for (int k2 = 0; k2 < 2; ++k2) {
            bf16x8 a[4], b[4];
            const int s0 = k2 * 8 + fq * 2;
#pragma unroll
            for (int m = 0; m < 4; ++m) {
                const int r = wr * 64 + m * 16 + fr;        // r&15 == fr
                f32x4 va = *(const f32x4*)&As[cur][r][((s0    ) ^ fr) * 4];
                f32x4 vb = *(const f32x4*)&As[cur][r][((s0 + 1) ^ fr) * 4];
                u16x8 w;
                w[0] = cf(va[0]); w[1] = cf(va[1]); w[2] = cf(va[2]); w[3] = cf(va[3]);
                w[4] = cf(vb[0]); w[5] = cf(vb[1]); w[6] = cf(vb[2]); w[7] = cf(vb[3]);
                union { u16x8 u; bf16x8 b; } cvtu; cvtu.u = w;
                a[m] = cvtu.b;
            }
            const int cs = ((k2 * 4 + fq) ^ cxB) * 8;
#pragma unroll
            for (int n = 0; n < 4; ++n)
                b[n] = *(const bf16x8*)&Bs[cur][wc * 64 + n * 16 + fr][cs];
#pragma unroll
            for (int m = 0; m < 4; ++m)
#pragma unroll
                for (int n = 0; n < 4; ++n)
                    acc[m][n] = __builtin_amdgcn_mfma_f32_16x16x32_bf16(a[m], b[n], acc[m][n], 0, 0, 0);
        }
        asm volatile("" ::: "memory");              // pin LDS reads above B2
        __builtin_amdgcn_s_barrier();               // B2: buf[cur] reusable
    }

    ushort* P = part + (int64_t)ks * NB * POSEC;
    const int mbase = mt * 128 + wr * 64, nbase = nt * 256 + wc * 64;
#pragma unroll
    for (int m = 0; m < 4; ++m)
#pragma unroll
        for (int n = 0; n < 4; ++n) {
            int row0 = mbase + m * 16 + fq * 4;
            int col  = nbase + n * 16 + fr;
#pragma unroll
            for (int r = 0; r < 4; ++r)
                P[(int64_t)(row0 + r) * POSEC + col] = f2b(acc[m][n][r]);
        }
}

// ---------------- reduce: A2 = bf16(sum_ks bf16part + b1) (R12-proven) ----------------
__global__ __launch_bounds__(256) void reduce_kernel(const ushort* __restrict__ part,
                                                     const float* __restrict__ b1,
                                                     u16x8* __restrict__ A2) {
    const int gid = blockIdx.x * 256 + threadIdx.x;     // 131072 threads, 8 elems each
    const int64_t e0 = (int64_t)gid * 8;
    float s[8] = {};
#pragma unroll
    for (int k = 0; k < KS; ++k) {
        u16x8 p = *(const u16x8*)(part + (int64_t)k * (NB * POSEC) + e0);
#pragma unroll
        for (int j = 0; j < 8; ++j) s[j] += b2f(p[j]);
    }
    const int col = (int)(e0 & 511);
    f4v b0 = *(const f4v*)&b1[col];
    f4v b4 = *(const f4v*)&b1[col + 4];
    u16x8 o;
#pragma unroll
    for (int j = 0; j < 4; ++j) { o[j] = f2b(s[j] + b0[j]); o[j+4] = f2b(s[j+4] + b4[j]); }
    A2[gid] = o;
}

// ---------------- GEMM2: mem = A2 @ W2b^T + b2 (R9-proven, swizzled) ----------------
__global__ __launch_bounds__(256) void gemm2_kernel(const ushort* __restrict__ A2,
                                                    const ushort* __restrict__ w2b,
                                                    const float* __restrict__ b2,
                                                    float* __restrict__ mem) {
    __shared__ ushort As[64][64];
    __shared__ ushort Bs[64][64];
    const int t = threadIdx.x;
    const int l = t & 63, wid = t >> 6;
    const int wr = wid >> 1, wc = wid & 1;
    const int mt = blockIdx.x >> 3, nt = blockIdx.x & 7;

    f32x4 acc[2][2] = {};
    const ushort* aG = A2  + (int64_t)(mt * 64) * POSEC;
    const ushort* bG = w2b + (int64_t)(nt * 64) * POSEC;
    const int srow = t >> 3;
    const int scol = (((t & 7) ^ ((t >> 3) & 7))) * 8;
    const int fr = l & 15, fq = l >> 4;
    const int cx = fr & 7;

    for (int k0 = 0; k0 < POSEC; k0 += 64) {
#pragma unroll
        for (int i = 0; i < 2; ++i) {
            gload_lds16(aG + (int64_t)(i * 32 + srow) * POSEC + k0 + scol,
                        (char*)&As[0][0] + i * 4096 + wid * 1024);
            gload_lds16(bG + (int64_t)(i * 32 + srow) * POSEC + k0 + scol,
                        (char*)&Bs[0][0] + i * 4096 + wid * 1024);
        }
        __syncthreads();
#pragma unroll
        for (int k2 = 0; k2 < 2; ++k2) {
            const int cs = ((k2 * 4 + fq) ^ cx) * 8;
            bf16x8 a[2], b[2];
#pragma unroll
            for (int m = 0; m < 2; ++m)
                a[m] = *(const bf16x8*)&As[wr * 32 + m * 16 + fr][cs];
#pragma unroll
            for (int n = 0; n < 2; ++n)
                b[n] = *(const bf16x8*)&Bs[wc * 32 + n * 16 + fr][cs];
#pragma unroll
            for (int m = 0; m < 2; ++m)
#pragma unroll
                for (int n = 0; n < 2; ++n)
                    acc[m][n] = __builtin_amdgcn_mfma_f32_16x16x32_bf16(a[m], b[n], acc[m][n], 0, 0, 0);
        }
        __syncthreads();
    }

    const int mbase = mt * 64 + wr * 32, nbase = nt * 64 + wc * 32;
#pragma unroll
    for (int m = 0; m < 2; ++m)
#pragma unroll
        for (int n = 0; n < 2; ++n) {
            int row0 = mbase + m * 16 + fq * 4;
            int col  = nbase + n * 16 + fr;
            float bias = b2[col];
#pragma unroll
            for (int r = 0; r < 4; ++r)
                mem[(int64_t)(row0 + r) * POSEC + col] = acc[m][n][r] + bias;
        }
}

// ---------------- score + sigmoid + blend + copy ----------------
__global__ __launch_bounds__(256) void blend_kernel(const float* __restrict__ pred,
                                                    const float* __restrict__ mem,
                                                    float* __restrict__ out) {
    const int b = blockIdx.x;
    const int t = threadIdx.x;
    __shared__ float sm[POSEC];
    __shared__ float sg[CHUNKC];

    sm[t]       = mem[(int64_t)b * POSEC + t];
    sm[t + 256] = mem[(int64_t)b * POSEC + 256 + t];
    __syncthreads();

    const int l = t & 63, wid = t >> 6;
    const float4* sm4 = (const float4*)sm;
    const float4* p4 = (const float4*)pred + (int64_t)b * 16384;
    float4* o4 = (float4*)out + (int64_t)b * 16384;

#pragma unroll
    for (int ci = 0; ci < 8; ++ci) {
        int c = wid * 8 + ci;
        float4 h0 = p4[c * 128 + l * 2];
        float4 h1 = p4[c * 128 + l * 2 + 1];
        float4 m0 = sm4[l * 2];
        float4 m1 = sm4[l * 2 + 1];
        float s = h0.x * m0.x + h0.y * m0.y + h0.z * m0.z + h0.w * m0.w
                + h1.x * m1.x + h1.y * m1.y + h1.z * m1.z + h1.w * m1.w;
#pragma unroll
        for (int o = 32; o; o >>= 1) s += __shfl_xor(s, o);
        if (l == 0) sg[c] = 1.0f / (1.0f + expf(-s));
    }
    __syncthreads();

#pragma unroll
    for (int i = 0; i < 16; ++i) {
        int idx = i * 256 + t;
        int row = idx >> 7, c4 = idx & 127;
        float g = sg[row];
        float4 h = p4[idx];
        float4 m = sm4[c4];
        float4 r;
        r.x = g * h.x + (1.0f - g) * m.x;
        r.y = g * h.y + (1.0f - g) * m.y;
        r.z = g * h.z + (1.0f - g) * m.z;
        r.w = g * h.w + (1.0f - g) * m.w;
        o4[idx] = r;
    }
#pragma unroll
    for (int i = 0; i < 48; ++i) {
        int idx = 4096 + i * 256 + t;
        f4v h = __builtin_nontemporal_load((const f4v*)p4 + idx);
        __builtin_nontemporal_store(h, (f4v*)o4 + idx);
    }
}

// ---------------- launch ----------------

extern "C" void kernel_launch(void* const* d_in, const int* in_sizes, int n_in,
                              void* d_out, int out_size, void* d_ws, size_t ws_size,
                              hipStream_t stream) {
    const float* init = (const float*)d_in[0];
    const float* pred = (const float*)d_in[1];
    const float* W1   = (const float*)d_in[2];
    const float* b1   = (const float*)d_in[3];
    const float* W2   = (const float*)d_in[4];
    const float* b2   = (const float*)d_in[5];
    float* out = (float*)d_out;

    char* ws = (char*)d_ws;
    ushort* w1b  = (ushort*)(ws);                       // 16777216 B
    ushort* w2b  = (ushort*)(ws + 16777216);            //   524288 B
    ushort* part = (ushort*)(ws + 17301504);            // 16777216 B (8 x 2048x512 bf16)
    ushort* A2   = (ushort*)(ws + 34078720);            //  2097152 B
    float*  mem  = (float*) (ws + 36175872);            //  4194304 B
    // total 40,370,176 B

    cvt_w_kernel<<<1024, 256, 0, stream>>>((const float4*)W1, (const float4*)W2,
                                           (ushort4*)w1b, (ushort4*)w2b);
    gemm1_kernel<<<256, 512, 0, stream>>>(init, w1b, part);
    reduce_kernel<<<512, 256, 0, stream>>>(part, b1, (u16x8*)A2);
    gemm2_kernel<<<256, 256, 0, stream>>>(A2, w2b, b2, mem);
    blend_kernel<<<NB, 256, 0, stream>>>(pred, mem, out);
}